// Round 1
// baseline (127.787 us; speedup 1.0000x reference)
//
#include <hip/hip_runtime.h>
#include <math.h>

// Problem geometry (fixed by the reference): feat_erb [64,1,16384,32] f32,
// state [1,1,32] f32. Outputs: feat_out [64,1,16384,32] then final_state
// [64,1,32], concatenated flat in d_out (all f32).
#define B   64
#define T   16384
#define F   32
#define NC  256          // chunks along t
#define L   64           // T / NC
#define FG  8            // F / 4 (float4 groups)
#define FEAT_N (B * T * F)   // 33554432

static constexpr float ALPHA = 0.99f;
static constexpr float OMA   = 1.0f - 0.99f;      // (1 - alpha) in f32
static constexpr float INV40 = 1.0f / 40.0f;

// Pass 1: per (b, chunk, f-group) compute the chunk aggregate c = state after
// L steps starting from 0.  tid = b*2048 + chunk*8 + fg.
__global__ __launch_bounds__(256)
void ema_pass1(const float* __restrict__ x, float4* __restrict__ c) {
    int tid   = blockIdx.x * 256 + threadIdx.x;
    int fg    = tid & (FG - 1);
    int chunk = (tid >> 3) & (NC - 1);
    int b     = tid >> 11;

    const float4* xp = reinterpret_cast<const float4*>(x)
                     + (size_t)(b * T + chunk * L) * FG + fg;

    float sx = 0.f, sy = 0.f, sz = 0.f, sw = 0.f;
#pragma unroll 8
    for (int i = 0; i < L; ++i) {
        float4 v = xp[(size_t)i * FG];
        sx = fmaf(ALPHA, sx, OMA * v.x);
        sy = fmaf(ALPHA, sy, OMA * v.y);
        sz = fmaf(ALPHA, sz, OMA * v.z);
        sw = fmaf(ALPHA, sw, OMA * v.w);
    }
    c[tid] = make_float4(sx, sy, sz, sw);
}

// Pass 2: per (b, f) sequentially combine the NC chunk aggregates:
//   s_{k+1} = aL * s_k + c_k,  recording each chunk's starting state.
// Also writes the final state output.  2048 threads total.
__global__ __launch_bounds__(256)
void ema_pass2(const float* __restrict__ state,
               const float* __restrict__ c,
               float* __restrict__ sstart,
               float* __restrict__ fstate,
               float aL) {
    int tid = blockIdx.x * 256 + threadIdx.x;   // b*F + f
    int f   = tid & (F - 1);
    int b   = tid >> 5;

    float s = state[f];
    const float* cp = c      + (size_t)b * NC * F + f;
    float*       sp = sstart + (size_t)b * NC * F + f;
#pragma unroll 4
    for (int k = 0; k < NC; ++k) {
        sp[k * F] = s;
        s = fmaf(aL, s, cp[k * F]);
    }
    fstate[b * F + f] = s;
}

// Pass 3: per (b, chunk, f-group) rescan the chunk from its exact starting
// state and emit out = (x - s) / 40.
__global__ __launch_bounds__(256)
void ema_pass3(const float* __restrict__ x,
               const float4* __restrict__ sstart,
               float* __restrict__ out) {
    int tid   = blockIdx.x * 256 + threadIdx.x;
    int fg    = tid & (FG - 1);
    int chunk = (tid >> 3) & (NC - 1);
    int b     = tid >> 11;

    size_t base = (size_t)(b * T + chunk * L) * FG + fg;
    const float4* xp = reinterpret_cast<const float4*>(x)   + base;
    float4*       op = reinterpret_cast<float4*>(out)       + base;

    float4 s0 = sstart[tid];
    float sx = s0.x, sy = s0.y, sz = s0.z, sw = s0.w;
#pragma unroll 8
    for (int i = 0; i < L; ++i) {
        float4 v = xp[(size_t)i * FG];
        sx = fmaf(ALPHA, sx, OMA * v.x);
        sy = fmaf(ALPHA, sy, OMA * v.y);
        sz = fmaf(ALPHA, sz, OMA * v.z);
        sw = fmaf(ALPHA, sw, OMA * v.w);
        float4 o;
        o.x = (v.x - sx) * INV40;
        o.y = (v.y - sy) * INV40;
        o.z = (v.z - sz) * INV40;
        o.w = (v.w - sw) * INV40;
        op[(size_t)i * FG] = o;
    }
}

extern "C" void kernel_launch(void* const* d_in, const int* in_sizes, int n_in,
                              void* d_out, int out_size, void* d_ws, size_t ws_size,
                              hipStream_t stream) {
    const float* x     = (const float*)d_in[0];   // feat_erb [64,1,16384,32]
    const float* state = (const float*)d_in[1];   // state    [1,1,32]
    float* out = (float*)d_out;
    float* ws  = (float*)d_ws;

    float* c      = ws;                        // B*NC*F = 524288 floats (2 MB)
    float* sstart = ws + (size_t)B * NC * F;   // another 2 MB

    const float aL = (float)pow(0.99, (double)L);   // alpha^64

    ema_pass1<<<(B * NC * FG) / 256, 256, 0, stream>>>(x, (float4*)c);
    ema_pass2<<<(B * F) / 256, 256, 0, stream>>>(state, c, sstart, out + FEAT_N, aL);
    ema_pass3<<<(B * NC * FG) / 256, 256, 0, stream>>>(x, (const float4*)sstart, out);
}